// Round 3
// baseline (811.605 us; speedup 1.0000x reference)
//
#include <hip/hip_runtime.h>
#include <hip/hip_bf16.h>

// GIN 3-layer forward:
//   h1 = relu((x + segsum(x[src],dst)) @ W1 + b1)
//   h2 = relu((h1 + segsum(h1[src],dst)) @ Wm + bm)
//   out = (h2 + segsum(h2[src],dst)) @ W2 + b2
// Strategy: build CSR (by dst) once per launch, then 3x [gather-agg -> tiled GEMM].

#define FEAT 128

// ---------------- edge-index dtype detect (int64 vs int32 hedge) -------------
__global__ __launch_bounds__(64) void detect_i64_kernel(const int* __restrict__ ei,
                                                        int* __restrict__ flag) {
    if (threadIdx.x == 0 && blockIdx.x == 0) {
        int ok = 1;
        for (int t = 0; t < 64; ++t) {
            if (ei[2 * t + 1] != 0) { ok = 0; break; }
        }
        flag[0] = ok;  // 1 => data is int64 (high words zero), 0 => int32
    }
}

__device__ __forceinline__ int load_src(const int* ei, int E, int e, int is64) {
    return is64 ? ei[2 * e] : ei[e];
}
__device__ __forceinline__ int load_dst(const int* ei, int E, int e, int is64) {
    return is64 ? ei[2 * (E + e)] : ei[E + e];
}

// ---------------- CSR build ----------------
__global__ __launch_bounds__(256) void hist_kernel(const int* __restrict__ ei, int E,
                                                   const int* __restrict__ flag,
                                                   int* __restrict__ counts) {
    int e = blockIdx.x * 256 + threadIdx.x;
    if (e >= E) return;
    int is64 = flag[0];
    int d = load_dst(ei, E, e, is64);
    atomicAdd(&counts[d], 1);
}

__global__ __launch_bounds__(1024) void scan_block_sums(const int* __restrict__ counts,
                                                        int* __restrict__ partials, int N) {
    __shared__ int s[1024];
    int i = blockIdx.x * 1024 + threadIdx.x;
    s[threadIdx.x] = (i < N) ? counts[i] : 0;
    __syncthreads();
    for (int d = 512; d > 0; d >>= 1) {
        if (threadIdx.x < d) s[threadIdx.x] += s[threadIdx.x + d];
        __syncthreads();
    }
    if (threadIdx.x == 0) partials[blockIdx.x] = s[0];
}

__global__ __launch_bounds__(1024) void scan_partials(int* __restrict__ partials, int NB) {
    __shared__ int s[1024];
    int t = threadIdx.x;
    int v = (t < NB) ? partials[t] : 0;
    s[t] = v;
    __syncthreads();
    for (int d = 1; d < 1024; d <<= 1) {
        int add = (t >= d) ? s[t - d] : 0;
        __syncthreads();
        s[t] += add;
        __syncthreads();
    }
    if (t < NB) partials[t] = s[t] - v;  // exclusive
}

__global__ __launch_bounds__(1024) void scan_final(const int* __restrict__ counts,
                                                   const int* __restrict__ partials,
                                                   int* __restrict__ row_start,
                                                   int* __restrict__ cursor, int N) {
    __shared__ int s[1024];
    int t = threadIdx.x;
    int i = blockIdx.x * 1024 + t;
    int c = (i < N) ? counts[i] : 0;
    s[t] = c;
    __syncthreads();
    for (int d = 1; d < 1024; d <<= 1) {
        int add = (t >= d) ? s[t - d] : 0;
        __syncthreads();
        s[t] += add;
        __syncthreads();
    }
    int ex = partials[blockIdx.x] + s[t] - c;  // exclusive prefix
    if (i < N) {
        row_start[i] = ex;
        cursor[i] = ex;
    }
    if (i == N - 1) row_start[N] = ex + c;
}

__global__ __launch_bounds__(256) void scatter_kernel(const int* __restrict__ ei, int E,
                                                      const int* __restrict__ flag,
                                                      int* __restrict__ cursor,
                                                      int* __restrict__ col) {
    int e = blockIdx.x * 256 + threadIdx.x;
    if (e >= E) return;
    int is64 = flag[0];
    int srcv = load_src(ei, E, e, is64);
    int d = load_dst(ei, E, e, is64);
    int p = atomicAdd(&cursor[d], 1);
    col[p] = srcv;
}

// ---------------- aggregation: Y[n] = X[n] + sum_{j in CSR row n} X[j] ----------
// one wave per node; lane handles 2 features (float2) -> 512B coalesced per row read
__global__ __launch_bounds__(256) void agg_kernel(const float* __restrict__ X,
                                                  const int* __restrict__ row_start,
                                                  const int* __restrict__ col,
                                                  float* __restrict__ Y, int N) {
    int w = (blockIdx.x * 256 + threadIdx.x) >> 6;
    int lane = threadIdx.x & 63;
    if (w >= N) return;
    size_t fo = (size_t)w * FEAT + lane * 2;
    float2 acc = *(const float2*)(X + fo);
    int s = row_start[w], e = row_start[w + 1];
    int k = s;
    for (; k + 1 < e; k += 2) {
        int j0 = col[k], j1 = col[k + 1];
        float2 v0 = *(const float2*)(X + (size_t)j0 * FEAT + lane * 2);
        float2 v1 = *(const float2*)(X + (size_t)j1 * FEAT + lane * 2);
        acc.x += v0.x + v1.x;
        acc.y += v0.y + v1.y;
    }
    if (k < e) {
        int j = col[k];
        float2 v = *(const float2*)(X + (size_t)j * FEAT + lane * 2);
        acc.x += v.x;
        acc.y += v.y;
    }
    *(float2*)(Y + fo) = acc;
}

// ---------------- tiled f32 GEMM: C[M,NCOL] = A[M,128] @ W[128,NCOL] + b, opt relu ----
__global__ __launch_bounds__(256) void mlp_kernel(const float* __restrict__ A,
                                                  const float* __restrict__ W,
                                                  const float* __restrict__ bias,
                                                  float* __restrict__ C, int M, int NCOL,
                                                  int relu) {
    __shared__ __align__(16) float As[64][68];
    __shared__ __align__(16) float Ws[64][68];
    const int tid = threadIdx.x;
    const int row0 = blockIdx.x * 64;
    const int col0 = blockIdx.y * 64;
    const int tx = tid & 15, ty = tid >> 4;
    const int m0 = ty * 4, n0 = tx * 4;
    float4 acc[4];
#pragma unroll
    for (int i = 0; i < 4; ++i) acc[i] = make_float4(0.f, 0.f, 0.f, 0.f);

    for (int kh = 0; kh < 2; ++kh) {
        const int k0 = kh * 64;
        // stage A tile (64 rows x 64 k) as float4
#pragma unroll
        for (int i = 0; i < 4; ++i) {
            int linear = tid + i * 256;
            int m = linear >> 4;
            int kq = linear & 15;
            int gm = row0 + m;
            float4 v = make_float4(0.f, 0.f, 0.f, 0.f);
            if (gm < M) v = *(const float4*)(A + (size_t)gm * FEAT + k0 + kq * 4);
            *(float4*)(&As[m][kq * 4]) = v;
        }
        // stage W tile (64 k x 64 n)
#pragma unroll
        for (int i = 0; i < 4; ++i) {
            int linear = tid + i * 256;
            int kk = linear >> 4;
            int nq = linear & 15;
            float4 v = *(const float4*)(W + (size_t)(k0 + kk) * NCOL + col0 + nq * 4);
            *(float4*)(&Ws[kk][nq * 4]) = v;
        }
        __syncthreads();
#pragma unroll 4
        for (int k = 0; k < 64; k += 4) {
            float4 b0 = *(const float4*)(&Ws[k + 0][n0]);
            float4 b1 = *(const float4*)(&Ws[k + 1][n0]);
            float4 b2 = *(const float4*)(&Ws[k + 2][n0]);
            float4 b3 = *(const float4*)(&Ws[k + 3][n0]);
#pragma unroll
            for (int i = 0; i < 4; ++i) {
                float4 a = *(const float4*)(&As[m0 + i][k]);
                acc[i].x += a.x * b0.x + a.y * b1.x + a.z * b2.x + a.w * b3.x;
                acc[i].y += a.x * b0.y + a.y * b1.y + a.z * b2.y + a.w * b3.y;
                acc[i].z += a.x * b0.z + a.y * b1.z + a.z * b2.z + a.w * b3.z;
                acc[i].w += a.x * b0.w + a.y * b1.w + a.z * b2.w + a.w * b3.w;
            }
        }
        __syncthreads();
    }
    float4 bv = *(const float4*)(bias + col0 + n0);
#pragma unroll
    for (int i = 0; i < 4; ++i) {
        int gm = row0 + m0 + i;
        if (gm < M) {
            float4 o;
            o.x = acc[i].x + bv.x;
            o.y = acc[i].y + bv.y;
            o.z = acc[i].z + bv.z;
            o.w = acc[i].w + bv.w;
            if (relu) {
                o.x = fmaxf(o.x, 0.f);
                o.y = fmaxf(o.y, 0.f);
                o.z = fmaxf(o.z, 0.f);
                o.w = fmaxf(o.w, 0.f);
            }
            *(float4*)(C + (size_t)gm * NCOL + col0 + n0) = o;
        }
    }
}

extern "C" void kernel_launch(void* const* d_in, const int* in_sizes, int n_in,
                              void* d_out, int out_size, void* d_ws, size_t ws_size,
                              hipStream_t stream) {
    const float* x = (const float*)d_in[0];
    const int* ei = (const int*)d_in[1];
    const float* W1 = (const float*)d_in[2];
    const float* b1 = (const float*)d_in[3];
    const float* Wm = (const float*)d_in[4];
    const float* bm = (const float*)d_in[5];
    const float* W2 = (const float*)d_in[6];
    const float* b2 = (const float*)d_in[7];
    float* out = (float*)d_out;

    const int N = in_sizes[0] / FEAT;      // 100000
    const int E = in_sizes[1] / 2;         // 1600000
    const int NHID = FEAT;                 // 128
    const int OUTD = in_sizes[6] / NHID;   // 64

    auto alignup = [](size_t v) { return (v + 255) & ~(size_t)255; };
    char* ws = (char*)d_ws;
    size_t off = 0;
    int* counts = (int*)(ws + off);    off += alignup((size_t)N * 4);
    int* row_start = (int*)(ws + off); off += alignup((size_t)(N + 1) * 4);
    int* cursor = (int*)(ws + off);    off += alignup((size_t)N * 4);
    int* partials = (int*)(ws + off);  off += alignup(1024 * 4);
    int* flag = (int*)(ws + off);      off += 256;
    int* col = (int*)(ws + off);       off += alignup((size_t)E * 4);
    float* Y = (float*)(ws + off);     off += alignup((size_t)N * FEAT * 4);
    float* H = (float*)(ws + off);     off += alignup((size_t)N * FEAT * 4);
    (void)ws_size;

    const int NB = (N + 1023) / 1024;

    // --- CSR build ---
    hipMemsetAsync(counts, 0, (size_t)N * 4, stream);
    detect_i64_kernel<<<1, 64, 0, stream>>>(ei, flag);
    hist_kernel<<<(E + 255) / 256, 256, 0, stream>>>(ei, E, flag, counts);
    scan_block_sums<<<NB, 1024, 0, stream>>>(counts, partials, N);
    scan_partials<<<1, 1024, 0, stream>>>(partials, NB);
    scan_final<<<NB, 1024, 0, stream>>>(counts, partials, row_start, cursor, N);
    scatter_kernel<<<(E + 255) / 256, 256, 0, stream>>>(ei, E, flag, cursor, col);

    const int aggBlocks = (N * 64 + 255) / 256;
    dim3 g128((N + 63) / 64, NHID / 64);
    dim3 g64((N + 63) / 64, OUTD / 64);

    // layer 1
    agg_kernel<<<aggBlocks, 256, 0, stream>>>(x, row_start, col, Y, N);
    mlp_kernel<<<g128, 256, 0, stream>>>(Y, W1, b1, H, N, NHID, 1);
    // layer 2
    agg_kernel<<<aggBlocks, 256, 0, stream>>>(H, row_start, col, Y, N);
    mlp_kernel<<<g128, 256, 0, stream>>>(Y, Wm, bm, H, N, NHID, 1);
    // layer 3
    agg_kernel<<<aggBlocks, 256, 0, stream>>>(H, row_start, col, Y, N);
    mlp_kernel<<<g64, 256, 0, stream>>>(Y, W2, b2, out, N, OUTD, 0);
}

// Round 4
// 726.759 us; speedup vs baseline: 1.1167x; 1.1167x over previous
//
#include <hip/hip_runtime.h>
#include <hip/hip_bf16.h>

// GIN 3-layer forward:
//   h1 = relu((x + segsum(x[src],dst)) @ W1 + b1)
//   h2 = relu((h1 + segsum(h1[src],dst)) @ Wm + bm)
//   out = (h2 + segsum(h2[src],dst)) @ W2 + b2
// CSR build via radix-partition counting sort (no random 4B global scatter),
// then 3x [gather-agg -> tiled GEMM].

#define FEAT 128
#define EPB 16384  // edges per block in phase A/B (256 thr x 64)

// ---------------- edge-index dtype detect (int64 vs int32 hedge) -------------
__global__ __launch_bounds__(64) void detect_i64_kernel(const int* __restrict__ ei,
                                                        int* __restrict__ flag) {
    if (threadIdx.x == 0 && blockIdx.x == 0) {
        int ok = 1;
        for (int t = 0; t < 64; ++t) {
            if (ei[2 * t + 1] != 0) { ok = 0; break; }
        }
        flag[0] = ok;  // 1 => int64 (high words zero), 0 => int32
    }
}

// ---------------- phase A: per-(bucket,block) histogram ----------------------
// bucket = dst >> 8 (256 nodes per bucket). NBUCK <= 512 required (N <= 131072).
__global__ __launch_bounds__(256) void phaseA_kernel(const int* __restrict__ ei, int E,
                                                     const int* __restrict__ flag,
                                                     int* __restrict__ G, int NBUCK,
                                                     int NBA) {
    __shared__ int hist[512];
    const int t = threadIdx.x;
    for (int i = t; i < NBUCK; i += 256) hist[i] = 0;
    __syncthreads();
    const int is64 = flag[0];
    const int base = blockIdx.x * EPB;
    const int lim = min(E, base + EPB);
    if (is64) {
        const int2* p = (const int2*)ei;
        for (int e = base + t; e < lim; e += 256) {
            int d = p[(size_t)E + e].x;
            atomicAdd(&hist[d >> 8], 1);
        }
    } else {
        for (int e = base + t; e < lim; e += 256) {
            int d = ei[(size_t)E + e];
            atomicAdd(&hist[d >> 8], 1);
        }
    }
    __syncthreads();
    for (int i = t; i < NBUCK; i += 256) G[i * NBA + blockIdx.x] = hist[i];
}

// ---------------- scan: exclusive scan of G (M = NBUCK*NBA entries) ----------
__global__ __launch_bounds__(1024) void scanG_kernel(const int* __restrict__ G,
                                                     int* __restrict__ Gsc, int M) {
    __shared__ int tot[1024];
    const int t = threadIdx.x;
    const int CH = (M + 1023) / 1024;
    const int lo = t * CH;
    const int hi = min(M, lo + CH);
    int sum = 0;
    for (int i = lo; i < hi; ++i) sum += G[i];
    tot[t] = sum;
    __syncthreads();
    for (int d = 1; d < 1024; d <<= 1) {
        int v = (t >= d) ? tot[t - d] : 0;
        __syncthreads();
        tot[t] += v;
        __syncthreads();
    }
    int run = tot[t] - sum;  // exclusive prefix of this thread's chunk
    for (int i = lo; i < hi; ++i) {
        int g = G[i];
        Gsc[i] = run;
        run += g;
    }
}

// ---------------- phase B: partition edges into bucket-contiguous records ----
__global__ __launch_bounds__(256) void phaseB_kernel(const int* __restrict__ ei, int E,
                                                     const int* __restrict__ flag,
                                                     const int* __restrict__ Gsc,
                                                     uint2* __restrict__ rec, int NBUCK,
                                                     int NBA) {
    __shared__ int cur[512];
    const int t = threadIdx.x;
    const int blk = blockIdx.x;
    for (int i = t; i < NBUCK; i += 256) cur[i] = Gsc[i * NBA + blk];
    __syncthreads();
    const int is64 = flag[0];
    const int base = blk * EPB;
    const int lim = min(E, base + EPB);
    if (is64) {
        const int2* p = (const int2*)ei;
        for (int e = base + t; e < lim; e += 256) {
            int s = p[e].x;
            int d = p[(size_t)E + e].x;
            int pos = atomicAdd(&cur[d >> 8], 1);
            rec[pos] = make_uint2((unsigned)s, (unsigned)d);
        }
    } else {
        for (int e = base + t; e < lim; e += 256) {
            int s = ei[e];
            int d = ei[(size_t)E + e];
            int pos = atomicAdd(&cur[d >> 8], 1);
            rec[pos] = make_uint2((unsigned)s, (unsigned)d);
        }
    }
}

// ---------------- phase C: per-bucket counting sort -> CSR col + row_start ---
__global__ __launch_bounds__(256) void phaseC_kernel(const uint2* __restrict__ rec,
                                                     const int* __restrict__ Gsc,
                                                     int* __restrict__ row_start,
                                                     int* __restrict__ col, int N, int E,
                                                     int NBUCK, int NBA) {
    __shared__ int cnt[256];
    __shared__ int scn[256];
    const int b = blockIdx.x;
    const int t = threadIdx.x;
    const int start = Gsc[b * NBA];
    const int end = (b + 1 < NBUCK) ? Gsc[(b + 1) * NBA] : E;
    cnt[t] = 0;
    __syncthreads();
    for (int i = start + t; i < end; i += 256) {
        atomicAdd(&cnt[rec[i].y & 255], 1);
    }
    __syncthreads();
    int c = cnt[t];
    scn[t] = c;
    __syncthreads();
    for (int d = 1; d < 256; d <<= 1) {
        int v = (t >= d) ? scn[t - d] : 0;
        __syncthreads();
        scn[t] += v;
        __syncthreads();
    }
    const int excl = scn[t] - c;
    const int node = b * 256 + t;
    if (node < N) row_start[node] = start + excl;
    if (b == NBUCK - 1 && t == 0) row_start[N] = E;
    cnt[t] = excl;  // reuse as relative cursor
    __syncthreads();
    for (int i = start + t; i < end; i += 256) {
        uint2 r = rec[i];
        int pos = start + atomicAdd(&cnt[r.y & 255], 1);
        col[pos] = (int)r.x;
    }
}

// ---------------- aggregation: Y[n] = X[n] + sum_{j in CSR row n} X[j] -------
// one wave per node; lane handles 2 features (float2); 4-deep unroll for MLP
__global__ __launch_bounds__(256) void agg_kernel(const float* __restrict__ X,
                                                  const int* __restrict__ row_start,
                                                  const int* __restrict__ col,
                                                  float* __restrict__ Y, int N) {
    int w = (blockIdx.x * 256 + threadIdx.x) >> 6;
    int lane = threadIdx.x & 63;
    if (w >= N) return;
    size_t fo = (size_t)w * FEAT + lane * 2;
    float2 acc = *(const float2*)(X + fo);
    int s = row_start[w], e = row_start[w + 1];
    int k = s;
    for (; k + 3 < e; k += 4) {
        int j0 = col[k], j1 = col[k + 1], j2 = col[k + 2], j3 = col[k + 3];
        float2 v0 = *(const float2*)(X + (size_t)j0 * FEAT + lane * 2);
        float2 v1 = *(const float2*)(X + (size_t)j1 * FEAT + lane * 2);
        float2 v2 = *(const float2*)(X + (size_t)j2 * FEAT + lane * 2);
        float2 v3 = *(const float2*)(X + (size_t)j3 * FEAT + lane * 2);
        acc.x += (v0.x + v1.x) + (v2.x + v3.x);
        acc.y += (v0.y + v1.y) + (v2.y + v3.y);
    }
    for (; k < e; ++k) {
        int j = col[k];
        float2 v = *(const float2*)(X + (size_t)j * FEAT + lane * 2);
        acc.x += v.x;
        acc.y += v.y;
    }
    *(float2*)(Y + fo) = acc;
}

// ---------------- tiled f32 GEMM: C[M,NCOL] = A[M,128] @ W[128,NCOL] + b -----
__global__ __launch_bounds__(256) void mlp_kernel(const float* __restrict__ A,
                                                  const float* __restrict__ W,
                                                  const float* __restrict__ bias,
                                                  float* __restrict__ C, int M, int NCOL,
                                                  int relu) {
    __shared__ __align__(16) float As[64][68];
    __shared__ __align__(16) float Ws[64][68];
    const int tid = threadIdx.x;
    const int row0 = blockIdx.x * 64;
    const int col0 = blockIdx.y * 64;
    const int tx = tid & 15, ty = tid >> 4;
    const int m0 = ty * 4, n0 = tx * 4;
    float4 acc[4];
#pragma unroll
    for (int i = 0; i < 4; ++i) acc[i] = make_float4(0.f, 0.f, 0.f, 0.f);

    for (int kh = 0; kh < 2; ++kh) {
        const int k0 = kh * 64;
#pragma unroll
        for (int i = 0; i < 4; ++i) {
            int linear = tid + i * 256;
            int m = linear >> 4;
            int kq = linear & 15;
            int gm = row0 + m;
            float4 v = make_float4(0.f, 0.f, 0.f, 0.f);
            if (gm < M) v = *(const float4*)(A + (size_t)gm * FEAT + k0 + kq * 4);
            *(float4*)(&As[m][kq * 4]) = v;
        }
#pragma unroll
        for (int i = 0; i < 4; ++i) {
            int linear = tid + i * 256;
            int kk = linear >> 4;
            int nq = linear & 15;
            float4 v = *(const float4*)(W + (size_t)(k0 + kk) * NCOL + col0 + nq * 4);
            *(float4*)(&Ws[kk][nq * 4]) = v;
        }
        __syncthreads();
#pragma unroll 4
        for (int k = 0; k < 64; k += 4) {
            float4 b0 = *(const float4*)(&Ws[k + 0][n0]);
            float4 b1 = *(const float4*)(&Ws[k + 1][n0]);
            float4 b2 = *(const float4*)(&Ws[k + 2][n0]);
            float4 b3 = *(const float4*)(&Ws[k + 3][n0]);
#pragma unroll
            for (int i = 0; i < 4; ++i) {
                float4 a = *(const float4*)(&As[m0 + i][k]);
                acc[i].x += a.x * b0.x + a.y * b1.x + a.z * b2.x + a.w * b3.x;
                acc[i].y += a.x * b0.y + a.y * b1.y + a.z * b2.y + a.w * b3.y;
                acc[i].z += a.x * b0.z + a.y * b1.z + a.z * b2.z + a.w * b3.z;
                acc[i].w += a.x * b0.w + a.y * b1.w + a.z * b2.w + a.w * b3.w;
            }
        }
        __syncthreads();
    }
    float4 bv = *(const float4*)(bias + col0 + n0);
#pragma unroll
    for (int i = 0; i < 4; ++i) {
        int gm = row0 + m0 + i;
        if (gm < M) {
            float4 o;
            o.x = acc[i].x + bv.x;
            o.y = acc[i].y + bv.y;
            o.z = acc[i].z + bv.z;
            o.w = acc[i].w + bv.w;
            if (relu) {
                o.x = fmaxf(o.x, 0.f);
                o.y = fmaxf(o.y, 0.f);
                o.z = fmaxf(o.z, 0.f);
                o.w = fmaxf(o.w, 0.f);
            }
            *(float4*)(C + (size_t)gm * NCOL + col0 + n0) = o;
        }
    }
}

extern "C" void kernel_launch(void* const* d_in, const int* in_sizes, int n_in,
                              void* d_out, int out_size, void* d_ws, size_t ws_size,
                              hipStream_t stream) {
    const float* x = (const float*)d_in[0];
    const int* ei = (const int*)d_in[1];
    const float* W1 = (const float*)d_in[2];
    const float* b1 = (const float*)d_in[3];
    const float* Wm = (const float*)d_in[4];
    const float* bm = (const float*)d_in[5];
    const float* W2 = (const float*)d_in[6];
    const float* b2 = (const float*)d_in[7];
    float* out = (float*)d_out;

    const int N = in_sizes[0] / FEAT;      // 100000
    const int E = in_sizes[1] / 2;         // 1600000
    const int NHID = FEAT;                 // 128
    const int OUTD = in_sizes[6] / NHID;   // 64

    const int NBA = (E + EPB - 1) / EPB;   // 98
    const int NBUCK = (N + 255) >> 8;      // 391 (<=512 required)
    const int M = NBUCK * NBA;

    auto alignup = [](size_t v) { return (v + 255) & ~(size_t)255; };
    char* ws = (char*)d_ws;
    size_t off = 0;
    int* G = (int*)(ws + off);         off += alignup((size_t)M * 4);
    int* Gsc = (int*)(ws + off);       off += alignup((size_t)M * 4);
    int* row_start = (int*)(ws + off); off += alignup((size_t)(N + 1) * 4);
    int* flag = (int*)(ws + off);      off += 256;
    int* col = (int*)(ws + off);       off += alignup((size_t)E * 4);
    float* Y = (float*)(ws + off);     off += alignup((size_t)N * FEAT * 4);
    float* H = (float*)(ws + off);     off += alignup((size_t)N * FEAT * 4);
    (void)ws_size;
    // rec (E x 8B) aliases Y: consumed by phaseC strictly before agg1 writes Y.
    uint2* rec = (uint2*)Y;

    // --- CSR build (counting sort) ---
    detect_i64_kernel<<<1, 64, 0, stream>>>(ei, flag);
    phaseA_kernel<<<NBA, 256, 0, stream>>>(ei, E, flag, G, NBUCK, NBA);
    scanG_kernel<<<1, 1024, 0, stream>>>(G, Gsc, M);
    phaseB_kernel<<<NBA, 256, 0, stream>>>(ei, E, flag, Gsc, rec, NBUCK, NBA);
    phaseC_kernel<<<NBUCK, 256, 0, stream>>>(rec, Gsc, row_start, col, N, E, NBUCK, NBA);

    const int aggBlocks = (N * 64 + 255) / 256;
    dim3 g128((N + 63) / 64, NHID / 64);
    dim3 g64((N + 63) / 64, OUTD / 64);

    // layer 1
    agg_kernel<<<aggBlocks, 256, 0, stream>>>(x, row_start, col, Y, N);
    mlp_kernel<<<g128, 256, 0, stream>>>(Y, W1, b1, H, N, NHID, 1);
    // layer 2
    agg_kernel<<<aggBlocks, 256, 0, stream>>>(H, row_start, col, Y, N);
    mlp_kernel<<<g128, 256, 0, stream>>>(Y, Wm, bm, H, N, NHID, 1);
    // layer 3
    agg_kernel<<<aggBlocks, 256, 0, stream>>>(H, row_start, col, Y, N);
    mlp_kernel<<<g64, 256, 0, stream>>>(Y, W2, b2, out, N, OUTD, 0);
}

// Round 10
// 586.056 us; speedup vs baseline: 1.3849x; 1.2401x over previous
//
#include <hip/hip_runtime.h>
#include <hip/hip_bf16.h>

// GIN 3-layer forward, bf16 data plane / f32 compute:
//   cast x -> bf16 table
//   3x [gather-agg (bf16 in, f32 accum, bf16 out) -> tiled GEMM (bf16 A, f32 W/acc)]
// CSR build via radix-partition counting sort (validated round 4).

#define FEAT 128
#define EPB 16384  // edges per block in phase A/B

typedef unsigned short ushort_t;

__device__ __forceinline__ float bf2f(unsigned int u16) {
    union { unsigned int i; float f; } v;
    v.i = u16 << 16;
    return v.f;
}
__device__ __forceinline__ ushort_t f2bf(float f) {
    union { float f; unsigned int i; } v;
    v.f = f;
    unsigned int x = v.i;
    return (ushort_t)((x + 0x7FFFu + ((x >> 16) & 1u)) >> 16);  // RNE
}

// ---------------- edge-index dtype detect (int64 vs int32 hedge) -------------
__global__ __launch_bounds__(64) void detect_i64_kernel(const int* __restrict__ ei,
                                                        int* __restrict__ flag) {
    if (threadIdx.x == 0 && blockIdx.x == 0) {
        int ok = 1;
        for (int t = 0; t < 64; ++t) {
            if (ei[2 * t + 1] != 0) { ok = 0; break; }
        }
        flag[0] = ok;  // 1 => int64 (high words zero), 0 => int32
    }
}

// ---------------- cast: f32 -> bf16 table ------------------------------------
__global__ __launch_bounds__(256) void cast_kernel(const float* __restrict__ X,
                                                   ushort_t* __restrict__ Xb, int total4) {
    for (int i = blockIdx.x * 256 + threadIdx.x; i < total4; i += gridDim.x * 256) {
        float4 v = *(const float4*)(X + (size_t)i * 4);
        ushort4 o;
        o.x = f2bf(v.x); o.y = f2bf(v.y); o.z = f2bf(v.z); o.w = f2bf(v.w);
        *(ushort4*)(Xb + (size_t)i * 4) = o;
    }
}

// ---------------- phase A: per-(bucket,block) histogram ----------------------
__global__ __launch_bounds__(256) void phaseA_kernel(const int* __restrict__ ei, int E,
                                                     const int* __restrict__ flag,
                                                     int* __restrict__ G, int NBUCK,
                                                     int NBA) {
    __shared__ int hist[512];
    const int t = threadIdx.x;
    for (int i = t; i < NBUCK; i += 256) hist[i] = 0;
    __syncthreads();
    const int is64 = flag[0];
    const int base = blockIdx.x * EPB;
    const int lim = min(E, base + EPB);
    if (is64) {
        const int2* p = (const int2*)ei;
        for (int e = base + t; e < lim; e += 256) {
            int d = p[(size_t)E + e].x;
            atomicAdd(&hist[d >> 8], 1);
        }
    } else {
        for (int e = base + t; e < lim; e += 256) {
            int d = ei[(size_t)E + e];
            atomicAdd(&hist[d >> 8], 1);
        }
    }
    __syncthreads();
    for (int i = t; i < NBUCK; i += 256) G[i * NBA + blockIdx.x] = hist[i];
}

// ---------------- scan: exclusive scan of G ----------------------------------
__global__ __launch_bounds__(1024) void scanG_kernel(const int* __restrict__ G,
                                                     int* __restrict__ Gsc, int M) {
    __shared__ int tot[1024];
    const int t = threadIdx.x;
    const int CH = (M + 1023) / 1024;
    const int lo = t * CH;
    const int hi = min(M, lo + CH);
    int sum = 0;
    for (int i = lo; i < hi; ++i) sum += G[i];
    tot[t] = sum;
    __syncthreads();
    for (int d = 1; d < 1024; d <<= 1) {
        int v = (t >= d) ? tot[t - d] : 0;
        __syncthreads();
        tot[t] += v;
        __syncthreads();
    }
    int run = tot[t] - sum;
    for (int i = lo; i < hi; ++i) {
        int g = G[i];
        Gsc[i] = run;
        run += g;
    }
}

// ---------------- phase B: partition edges into bucket-contiguous records ----
__global__ __launch_bounds__(256) void phaseB_kernel(const int* __restrict__ ei, int E,
                                                     const int* __restrict__ flag,
                                                     const int* __restrict__ Gsc,
                                                     uint2* __restrict__ rec, int NBUCK,
                                                     int NBA) {
    __shared__ int cur[512];
    const int t = threadIdx.x;
    const int blk = blockIdx.x;
    for (int i = t; i < NBUCK; i += 256) cur[i] = Gsc[i * NBA + blk];
    __syncthreads();
    const int is64 = flag[0];
    const int base = blk * EPB;
    const int lim = min(E, base + EPB);
    if (is64) {
        const int2* p = (const int2*)ei;
        for (int e = base + t; e < lim; e += 256) {
            int s = p[e].x;
            int d = p[(size_t)E + e].x;
            int pos = atomicAdd(&cur[d >> 8], 1);
            rec[pos] = make_uint2((unsigned)s, (unsigned)d);
        }
    } else {
        for (int e = base + t; e < lim; e += 256) {
            int s = ei[e];
            int d = ei[(size_t)E + e];
            int pos = atomicAdd(&cur[d >> 8], 1);
            rec[pos] = make_uint2((unsigned)s, (unsigned)d);
        }
    }
}

// ---------------- phase C: per-bucket counting sort -> CSR col + row_start ---
__global__ __launch_bounds__(256) void phaseC_kernel(const uint2* __restrict__ rec,
                                                     const int* __restrict__ Gsc,
                                                     int* __restrict__ row_start,
                                                     int* __restrict__ col, int N, int E,
                                                     int NBUCK, int NBA) {
    __shared__ int cnt[256];
    __shared__ int scn[256];
    const int b = blockIdx.x;
    const int t = threadIdx.x;
    const int start = Gsc[b * NBA];
    const int end = (b + 1 < NBUCK) ? Gsc[(b + 1) * NBA] : E;
    cnt[t] = 0;
    __syncthreads();
    for (int i = start + t; i < end; i += 256) {
        atomicAdd(&cnt[rec[i].y & 255], 1);
    }
    __syncthreads();
    int c = cnt[t];
    scn[t] = c;
    __syncthreads();
    for (int d = 1; d < 256; d <<= 1) {
        int v = (t >= d) ? scn[t - d] : 0;
        __syncthreads();
        scn[t] += v;
        __syncthreads();
    }
    const int excl = scn[t] - c;
    const int node = b * 256 + t;
    if (node < N) row_start[node] = start + excl;
    if (b == NBUCK - 1 && t == 0) row_start[N] = E;
    cnt[t] = excl;
    __syncthreads();
    for (int i = start + t; i < end; i += 256) {
        uint2 r = rec[i];
        int pos = start + atomicAdd(&cnt[r.y & 255], 1);
        col[pos] = (int)r.x;
    }
}

// ---------------- aggregation (bf16): Y[n] = X[n] + sum_{j in row n} X[j] ----
// one wave per node; lane handles 2 features (ushort2 = 4B); f32 accumulate
__global__ __launch_bounds__(256) void agg_bf16_kernel(const ushort_t* __restrict__ Xb,
                                                       const int* __restrict__ row_start,
                                                       const int* __restrict__ col,
                                                       ushort_t* __restrict__ Yb, int N) {
    int w = (blockIdx.x * 256 + threadIdx.x) >> 6;
    int lane = threadIdx.x & 63;
    if (w >= N) return;
    const ushort2* X2 = (const ushort2*)Xb;
    size_t fo = (size_t)w * 64 + lane;  // row = 64 ushort2
    ushort2 sv = X2[fo];
    float ax = bf2f(sv.x), ay = bf2f(sv.y);
    int s = row_start[w], e = row_start[w + 1];
    int k = s;
    for (; k + 3 < e; k += 4) {
        int j0 = col[k], j1 = col[k + 1], j2 = col[k + 2], j3 = col[k + 3];
        ushort2 v0 = X2[(size_t)j0 * 64 + lane];
        ushort2 v1 = X2[(size_t)j1 * 64 + lane];
        ushort2 v2 = X2[(size_t)j2 * 64 + lane];
        ushort2 v3 = X2[(size_t)j3 * 64 + lane];
        ax += (bf2f(v0.x) + bf2f(v1.x)) + (bf2f(v2.x) + bf2f(v3.x));
        ay += (bf2f(v0.y) + bf2f(v1.y)) + (bf2f(v2.y) + bf2f(v3.y));
    }
    for (; k < e; ++k) {
        ushort2 v = X2[(size_t)col[k] * 64 + lane];
        ax += bf2f(v.x);
        ay += bf2f(v.y);
    }
    ushort2 o;
    o.x = f2bf(ax);
    o.y = f2bf(ay);
    ((ushort2*)Yb)[fo] = o;
}

// ---------------- tiled GEMM: C = A(bf16)[M,128] @ W(f32)[128,NCOL] + b ------
// f32 LDS/accumulate. mode: 1 = relu + bf16 store, 0 = plain f32 store.
__global__ __launch_bounds__(256) void mlp_kernel(const ushort_t* __restrict__ A,
                                                  const float* __restrict__ W,
                                                  const float* __restrict__ bias,
                                                  void* __restrict__ C, int M, int NCOL,
                                                  int mode) {
    __shared__ __align__(16) float As[64][68];
    __shared__ __align__(16) float Ws[64][68];
    const int tid = threadIdx.x;
    const int row0 = blockIdx.x * 64;
    const int col0 = blockIdx.y * 64;
    const int tx = tid & 15, ty = tid >> 4;
    const int m0 = ty * 4, n0 = tx * 4;
    float4 acc[4];
#pragma unroll
    for (int i = 0; i < 4; ++i) acc[i] = make_float4(0.f, 0.f, 0.f, 0.f);

    for (int kh = 0; kh < 2; ++kh) {
        const int k0 = kh * 64;
        // stage A tile (64 rows x 64 k): bf16x8 load -> f32 LDS
#pragma unroll
        for (int i = 0; i < 2; ++i) {
            int linear = tid + i * 256;  // 0..511
            int m = linear >> 3;         // row 0..63
            int ko = (linear & 7) * 8;   // 0,8,..,56
            int gm = row0 + m;
            float4 lo = make_float4(0.f, 0.f, 0.f, 0.f);
            float4 hi = make_float4(0.f, 0.f, 0.f, 0.f);
            if (gm < M) {
                uint4 raw = *(const uint4*)(A + (size_t)gm * FEAT + k0 + ko);
                lo.x = bf2f(raw.x & 0xffffu); lo.y = bf2f(raw.x >> 16);
                lo.z = bf2f(raw.y & 0xffffu); lo.w = bf2f(raw.y >> 16);
                hi.x = bf2f(raw.z & 0xffffu); hi.y = bf2f(raw.z >> 16);
                hi.z = bf2f(raw.w & 0xffffu); hi.w = bf2f(raw.w >> 16);
            }
            *(float4*)(&As[m][ko]) = lo;
            *(float4*)(&As[m][ko + 4]) = hi;
        }
        // stage W tile (64 k x 64 n), f32
#pragma unroll
        for (int i = 0; i < 4; ++i) {
            int linear = tid + i * 256;
            int kk = linear >> 4;
            int nq = linear & 15;
            float4 v = *(const float4*)(W + (size_t)(k0 + kk) * NCOL + col0 + nq * 4);
            *(float4*)(&Ws[kk][nq * 4]) = v;
        }
        __syncthreads();
#pragma unroll 4
        for (int k = 0; k < 64; k += 4) {
            float4 b0 = *(const float4*)(&Ws[k + 0][n0]);
            float4 b1 = *(const float4*)(&Ws[k + 1][n0]);
            float4 b2 = *(const float4*)(&Ws[k + 2][n0]);
            float4 b3 = *(const float4*)(&Ws[k + 3][n0]);
#pragma unroll
            for (int i = 0; i < 4; ++i) {
                float4 a = *(const float4*)(&As[m0 + i][k]);
                acc[i].x += a.x * b0.x + a.y * b1.x + a.z * b2.x + a.w * b3.x;
                acc[i].y += a.x * b0.y + a.y * b1.y + a.z * b2.y + a.w * b3.y;
                acc[i].z += a.x * b0.z + a.y * b1.z + a.z * b2.z + a.w * b3.z;
                acc[i].w += a.x * b0.w + a.y * b1.w + a.z * b2.w + a.w * b3.w;
            }
        }
        __syncthreads();
    }
    float4 bv = *(const float4*)(bias + col0 + n0);
#pragma unroll
    for (int i = 0; i < 4; ++i) {
        int gm = row0 + m0 + i;
        if (gm >= M) continue;
        float4 o;
        o.x = acc[i].x + bv.x;
        o.y = acc[i].y + bv.y;
        o.z = acc[i].z + bv.z;
        o.w = acc[i].w + bv.w;
        if (mode) {
            o.x = fmaxf(o.x, 0.f);
            o.y = fmaxf(o.y, 0.f);
            o.z = fmaxf(o.z, 0.f);
            o.w = fmaxf(o.w, 0.f);
            ushort4 ob;
            ob.x = f2bf(o.x); ob.y = f2bf(o.y); ob.z = f2bf(o.z); ob.w = f2bf(o.w);
            *(ushort4*)((ushort_t*)C + (size_t)gm * NCOL + col0 + n0) = ob;
        } else {
            *(float4*)((float*)C + (size_t)gm * NCOL + col0 + n0) = o;
        }
    }
}

extern "C" void kernel_launch(void* const* d_in, const int* in_sizes, int n_in,
                              void* d_out, int out_size, void* d_ws, size_t ws_size,
                              hipStream_t stream) {
    const float* x = (const float*)d_in[0];
    const int* ei = (const int*)d_in[1];
    const float* W1 = (const float*)d_in[2];
    const float* b1 = (const float*)d_in[3];
    const float* Wm = (const float*)d_in[4];
    const float* bm = (const float*)d_in[5];
    const float* W2 = (const float*)d_in[6];
    const float* b2 = (const float*)d_in[7];
    float* out = (float*)d_out;

    const int N = in_sizes[0] / FEAT;      // 100000
    const int E = in_sizes[1] / 2;         // 1600000
    const int NHID = FEAT;                 // 128
    const int OUTD = in_sizes[6] / NHID;   // 64

    const int NBA = (E + EPB - 1) / EPB;   // 98
    const int NBUCK = (N + 255) >> 8;      // 391 (<=512 required)
    const int M = NBUCK * NBA;

    auto alignup = [](size_t v) { return (v + 255) & ~(size_t)255; };
    char* ws = (char*)d_ws;
    size_t off = 0;
    int* G = (int*)(ws + off);           off += alignup((size_t)M * 4);
    int* Gsc = (int*)(ws + off);         off += alignup((size_t)M * 4);
    int* row_start = (int*)(ws + off);   off += alignup((size_t)(N + 1) * 4);
    int* flag = (int*)(ws + off);        off += 256;
    int* col = (int*)(ws + off);         off += alignup((size_t)E * 4);
    ushort_t* Xb = (ushort_t*)(ws + off); off += alignup((size_t)N * FEAT * 2);
    ushort_t* Yb = (ushort_t*)(ws + off); off += alignup((size_t)N * FEAT * 2);
    ushort_t* Hb = (ushort_t*)(ws + off); off += alignup((size_t)N * FEAT * 2);
    // rec (E x 8B = 12.8MB) aliases Yb (25.6MB): consumed by phaseC strictly
    // before agg1 writes Yb.
    uint2* rec = (uint2*)Yb;
    (void)ws_size;

    // --- bf16 table + CSR build ---
    cast_kernel<<<2048, 256, 0, stream>>>(x, Xb, N * FEAT / 4);
    detect_i64_kernel<<<1, 64, 0, stream>>>(ei, flag);
    phaseA_kernel<<<NBA, 256, 0, stream>>>(ei, E, flag, G, NBUCK, NBA);
    scanG_kernel<<<1, 1024, 0, stream>>>(G, Gsc, M);
    phaseB_kernel<<<NBA, 256, 0, stream>>>(ei, E, flag, Gsc, rec, NBUCK, NBA);
    phaseC_kernel<<<NBUCK, 256, 0, stream>>>(rec, Gsc, row_start, col, N, E, NBUCK, NBA);

    const int aggBlocks = (N * 64 + 255) / 256;
    dim3 g128((N + 63) / 64, NHID / 64);
    dim3 g64((N + 63) / 64, OUTD / 64);

    // layer 1
    agg_bf16_kernel<<<aggBlocks, 256, 0, stream>>>(Xb, row_start, col, Yb, N);
    mlp_kernel<<<g128, 256, 0, stream>>>(Yb, W1, b1, Hb, N, NHID, 1);
    // layer 2
    agg_bf16_kernel<<<aggBlocks, 256, 0, stream>>>(Hb, row_start, col, Yb, N);
    mlp_kernel<<<g128, 256, 0, stream>>>(Yb, Wm, bm, Hb, N, NHID, 1);
    // layer 3
    agg_bf16_kernel<<<aggBlocks, 256, 0, stream>>>(Hb, row_start, col, Yb, N);
    mlp_kernel<<<g64, 256, 0, stream>>>(Yb, W2, b2, out, N, OUTD, 0);
}

// Round 11
// 574.770 us; speedup vs baseline: 1.4121x; 1.0196x over previous
//
#include <hip/hip_runtime.h>
#include <hip/hip_bf16.h>

// GIN 3-layer forward, bf16 data plane / f32 compute.
// R11: (1) mlp rebuilt as 128xNT tile, 8x8/thread, register k-chunking (VALU-bound);
//      (2) agg 2 nodes/wave (32 lanes x ushort4) for 2x memory-level parallelism.
// CSR build via radix-partition counting sort (validated r4); agg/cast validated r10.

#define FEAT 128
#define EPB 16384  // edges per block in phase A/B

typedef unsigned short ushort_t;

__device__ __forceinline__ float bf2f(unsigned int u16) {
    union { unsigned int i; float f; } v;
    v.i = u16 << 16;
    return v.f;
}
__device__ __forceinline__ ushort_t f2bf(float f) {
    union { float f; unsigned int i; } v;
    v.f = f;
    unsigned int x = v.i;
    return (ushort_t)((x + 0x7FFFu + ((x >> 16) & 1u)) >> 16);  // RNE
}

// ---------------- edge-index dtype detect (int64 vs int32 hedge) -------------
__global__ __launch_bounds__(64) void detect_i64_kernel(const int* __restrict__ ei,
                                                        int* __restrict__ flag) {
    if (threadIdx.x == 0 && blockIdx.x == 0) {
        int ok = 1;
        for (int t = 0; t < 64; ++t) {
            if (ei[2 * t + 1] != 0) { ok = 0; break; }
        }
        flag[0] = ok;  // 1 => int64 (high words zero), 0 => int32
    }
}

// ---------------- cast: f32 -> bf16 table ------------------------------------
__global__ __launch_bounds__(256) void cast_kernel(const float* __restrict__ X,
                                                   ushort_t* __restrict__ Xb, int total4) {
    for (int i = blockIdx.x * 256 + threadIdx.x; i < total4; i += gridDim.x * 256) {
        float4 v = *(const float4*)(X + (size_t)i * 4);
        ushort4 o;
        o.x = f2bf(v.x); o.y = f2bf(v.y); o.z = f2bf(v.z); o.w = f2bf(v.w);
        *(ushort4*)(Xb + (size_t)i * 4) = o;
    }
}

// ---------------- phase A: per-(bucket,block) histogram ----------------------
__global__ __launch_bounds__(256) void phaseA_kernel(const int* __restrict__ ei, int E,
                                                     const int* __restrict__ flag,
                                                     int* __restrict__ G, int NBUCK,
                                                     int NBA) {
    __shared__ int hist[512];
    const int t = threadIdx.x;
    for (int i = t; i < NBUCK; i += 256) hist[i] = 0;
    __syncthreads();
    const int is64 = flag[0];
    const int base = blockIdx.x * EPB;
    const int lim = min(E, base + EPB);
    if (is64) {
        const int2* p = (const int2*)ei;
        for (int e = base + t; e < lim; e += 256) {
            int d = p[(size_t)E + e].x;
            atomicAdd(&hist[d >> 8], 1);
        }
    } else {
        for (int e = base + t; e < lim; e += 256) {
            int d = ei[(size_t)E + e];
            atomicAdd(&hist[d >> 8], 1);
        }
    }
    __syncthreads();
    for (int i = t; i < NBUCK; i += 256) G[i * NBA + blockIdx.x] = hist[i];
}

// ---------------- scan: exclusive scan of G ----------------------------------
__global__ __launch_bounds__(1024) void scanG_kernel(const int* __restrict__ G,
                                                     int* __restrict__ Gsc, int M) {
    __shared__ int tot[1024];
    const int t = threadIdx.x;
    const int CH = (M + 1023) / 1024;
    const int lo = t * CH;
    const int hi = min(M, lo + CH);
    int sum = 0;
    for (int i = lo; i < hi; ++i) sum += G[i];
    tot[t] = sum;
    __syncthreads();
    for (int d = 1; d < 1024; d <<= 1) {
        int v = (t >= d) ? tot[t - d] : 0;
        __syncthreads();
        tot[t] += v;
        __syncthreads();
    }
    int run = tot[t] - sum;
    for (int i = lo; i < hi; ++i) {
        int g = G[i];
        Gsc[i] = run;
        run += g;
    }
}

// ---------------- phase B: partition edges into bucket-contiguous records ----
__global__ __launch_bounds__(256) void phaseB_kernel(const int* __restrict__ ei, int E,
                                                     const int* __restrict__ flag,
                                                     const int* __restrict__ Gsc,
                                                     uint2* __restrict__ rec, int NBUCK,
                                                     int NBA) {
    __shared__ int cur[512];
    const int t = threadIdx.x;
    const int blk = blockIdx.x;
    for (int i = t; i < NBUCK; i += 256) cur[i] = Gsc[i * NBA + blk];
    __syncthreads();
    const int is64 = flag[0];
    const int base = blk * EPB;
    const int lim = min(E, base + EPB);
    if (is64) {
        const int2* p = (const int2*)ei;
        for (int e = base + t; e < lim; e += 256) {
            int s = p[e].x;
            int d = p[(size_t)E + e].x;
            int pos = atomicAdd(&cur[d >> 8], 1);
            rec[pos] = make_uint2((unsigned)s, (unsigned)d);
        }
    } else {
        for (int e = base + t; e < lim; e += 256) {
            int s = ei[e];
            int d = ei[(size_t)E + e];
            int pos = atomicAdd(&cur[d >> 8], 1);
            rec[pos] = make_uint2((unsigned)s, (unsigned)d);
        }
    }
}

// ---------------- phase C: per-bucket counting sort -> CSR col + row_start ---
__global__ __launch_bounds__(256) void phaseC_kernel(const uint2* __restrict__ rec,
                                                     const int* __restrict__ Gsc,
                                                     int* __restrict__ row_start,
                                                     int* __restrict__ col, int N, int E,
                                                     int NBUCK, int NBA) {
    __shared__ int cnt[256];
    __shared__ int scn[256];
    const int b = blockIdx.x;
    const int t = threadIdx.x;
    const int start = Gsc[b * NBA];
    const int end = (b + 1 < NBUCK) ? Gsc[(b + 1) * NBA] : E;
    cnt[t] = 0;
    __syncthreads();
    for (int i = start + t; i < end; i += 256) {
        atomicAdd(&cnt[rec[i].y & 255], 1);
    }
    __syncthreads();
    int c = cnt[t];
    scn[t] = c;
    __syncthreads();
    for (int d = 1; d < 256; d <<= 1) {
        int v = (t >= d) ? scn[t - d] : 0;
        __syncthreads();
        scn[t] += v;
        __syncthreads();
    }
    const int excl = scn[t] - c;
    const int node = b * 256 + t;
    if (node < N) row_start[node] = start + excl;
    if (b == NBUCK - 1 && t == 0) row_start[N] = E;
    cnt[t] = excl;
    __syncthreads();
    for (int i = start + t; i < end; i += 256) {
        uint2 r = rec[i];
        int pos = start + atomicAdd(&cnt[r.y & 255], 1);
        col[pos] = (int)r.x;
    }
}

// ---------------- aggregation (bf16): Y[n] = X[n] + sum_{j in row n} X[j] ----
// 2 nodes per wave: 32 lanes/node, lane handles 4 features (ushort4 = 8B).
// f32 accumulate; identical per-node summation order to r10 (bit-exact).
__global__ __launch_bounds__(256) void agg_bf16_kernel(const ushort_t* __restrict__ Xb,
                                                       const int* __restrict__ row_start,
                                                       const int* __restrict__ col,
                                                       ushort_t* __restrict__ Yb, int N) {
    int w = (blockIdx.x * 256 + threadIdx.x) >> 5;  // node per 32-lane half-wave
    int l32 = threadIdx.x & 31;
    if (w >= N) return;
    const ushort4* X4 = (const ushort4*)Xb;  // row = 32 ushort4
    size_t fo = (size_t)w * 32 + l32;
    ushort4 sv = X4[fo];
    float a0 = bf2f(sv.x), a1 = bf2f(sv.y), a2 = bf2f(sv.z), a3 = bf2f(sv.w);
    int s = row_start[w], e = row_start[w + 1];
    int k = s;
    for (; k + 3 < e; k += 4) {
        int j0 = col[k], j1 = col[k + 1], j2 = col[k + 2], j3 = col[k + 3];
        ushort4 v0 = X4[(size_t)j0 * 32 + l32];
        ushort4 v1 = X4[(size_t)j1 * 32 + l32];
        ushort4 v2 = X4[(size_t)j2 * 32 + l32];
        ushort4 v3 = X4[(size_t)j3 * 32 + l32];
        a0 += (bf2f(v0.x) + bf2f(v1.x)) + (bf2f(v2.x) + bf2f(v3.x));
        a1 += (bf2f(v0.y) + bf2f(v1.y)) + (bf2f(v2.y) + bf2f(v3.y));
        a2 += (bf2f(v0.z) + bf2f(v1.z)) + (bf2f(v2.z) + bf2f(v3.z));
        a3 += (bf2f(v0.w) + bf2f(v1.w)) + (bf2f(v2.w) + bf2f(v3.w));
    }
    for (; k < e; ++k) {
        ushort4 v = X4[(size_t)col[k] * 32 + l32];
        a0 += bf2f(v.x);
        a1 += bf2f(v.y);
        a2 += bf2f(v.z);
        a3 += bf2f(v.w);
    }
    ushort4 o;
    o.x = f2bf(a0);
    o.y = f2bf(a1);
    o.z = f2bf(a2);
    o.w = f2bf(a3);
    ((ushort4*)Yb)[fo] = o;
}

// ---------------- tiled GEMM: C = A(bf16)[M,128] @ W(f32)[128,NT] + b --------
// 128-row x NT-col tile, 256 threads, 8m x (NT/16)n per thread, m interleaved
// by 16 (conflict-free a-reads). K staged in 2 halves of 64. f32 accumulate.
// mode: 1 = relu + bf16 store, 0 = plain f32 store.
template <int NT>  // 128 or 64
__global__ __launch_bounds__(256, 2) void mlp_kernel(const ushort_t* __restrict__ A,
                                                     const float* __restrict__ W,
                                                     const float* __restrict__ bias,
                                                     void* __restrict__ C, int M, int NCOL,
                                                     int mode) {
    constexpr int NBN4 = NT / 64;  // float4s per thread along n (2 or 1)
    __shared__ __align__(16) float As[128][68];
    __shared__ __align__(16) float Ws[64][NT + 4];
    const int tid = threadIdx.x;
    const int row0 = blockIdx.x * 128;
    const int tx = tid & 15, ty = tid >> 4;
    const int n0 = tx * (NBN4 * 4);

    float4 accL[8], accH[8];
#pragma unroll
    for (int i = 0; i < 8; ++i) {
        accL[i] = make_float4(0.f, 0.f, 0.f, 0.f);
        accH[i] = make_float4(0.f, 0.f, 0.f, 0.f);
    }

    for (int kh = 0; kh < 2; ++kh) {
        const int k0 = kh * 64;
        // stage A tile (128 rows x 64 k): bf16x8 -> f32 LDS
#pragma unroll
        for (int it = 0; it < 4; ++it) {
            int linear = tid + it * 256;  // 0..1023
            int m = linear >> 3;          // 0..127
            int ko = (linear & 7) * 8;    // 0,8,..,56
            int gm = row0 + m;
            float4 lo = make_float4(0.f, 0.f, 0.f, 0.f);
            float4 hi = make_float4(0.f, 0.f, 0.f, 0.f);
            if (gm < M) {
                uint4 raw = *(const uint4*)(A + (size_t)gm * FEAT + k0 + ko);
                lo.x = bf2f(raw.x & 0xffffu); lo.y = bf2f(raw.x >> 16);
                lo.z = bf2f(raw.y & 0xffffu); lo.w = bf2f(raw.y >> 16);
                hi.x = bf2f(raw.z & 0xffffu); hi.y = bf2f(raw.z >> 16);
                hi.z = bf2f(raw.w & 0xffffu); hi.w = bf2f(raw.w >> 16);
            }
            *(float4*)(&As[m][ko]) = lo;
            *(float4*)(&As[m][ko + 4]) = hi;
        }
        // stage W tile (64 k x NT n), f32
#pragma unroll
        for (int it = 0; it < NBN4 * 4; ++it) {
            int linear = tid + it * 256;  // 0..(64*NT/4 - 1)
            int kk, nq;
            if (NT == 128) { kk = linear >> 5; nq = linear & 31; }
            else           { kk = linear >> 4; nq = linear & 15; }
            float4 v = *(const float4*)(W + (size_t)(k0 + kk) * NCOL + nq * 4);
            *(float4*)(&Ws[kk][nq * 4]) = v;
        }
        __syncthreads();

        for (int kc = 0; kc < 64; kc += 4) {
            float4 a[8];
#pragma unroll
            for (int i = 0; i < 8; ++i) a[i] = *(const float4*)(&As[ty + 16 * i][kc]);
            float4 bL[4], bH[4];
#pragma unroll
            for (int j = 0; j < 4; ++j) {
                bL[j] = *(const float4*)(&Ws[kc + j][n0]);
                if (NBN4 == 2) bH[j] = *(const float4*)(&Ws[kc + j][n0 + 4]);
            }
#pragma unroll
            for (int i = 0; i < 8; ++i) {
                accL[i].x += a[i].x * bL[0].x + a[i].y * bL[1].x + a[i].z * bL[2].x + a[i].w * bL[3].x;
                accL[i].y += a[i].x * bL[0].y + a[i].y * bL[1].y + a[i].z * bL[2].y + a[i].w * bL[3].y;
                accL[i].z += a[i].x * bL[0].z + a[i].y * bL[1].z + a[i].z * bL[2].z + a[i].w * bL[3].z;
                accL[i].w += a[i].x * bL[0].w + a[i].y * bL[1].w + a[i].z * bL[2].w + a[i].w * bL[3].w;
                if (NBN4 == 2) {
                    accH[i].x += a[i].x * bH[0].x + a[i].y * bH[1].x + a[i].z * bH[2].x + a[i].w * bH[3].x;
                    accH[i].y += a[i].x * bH[0].y + a[i].y * bH[1].y + a[i].z * bH[2].y + a[i].w * bH[3].y;
                    accH[i].z += a[i].x * bH[0].z + a[i].y * bH[1].z + a[i].z * bH[2].z + a[i].w * bH[3].z;
                    accH[i].w += a[i].x * bH[0].w + a[i].y * bH[1].w + a[i].z * bH[2].w + a[i].w * bH[3].w;
                }
            }
        }
        __syncthreads();
    }

    float4 bvL = *(const float4*)(bias + n0);
    float4 bvH = (NBN4 == 2) ? *(const float4*)(bias + n0 + 4) : make_float4(0.f, 0.f, 0.f, 0.f);
#pragma unroll
    for (int i = 0; i < 8; ++i) {
        int gm = row0 + ty + 16 * i;
        if (gm >= M) continue;
        float4 oL, oH;
        oL.x = accL[i].x + bvL.x; oL.y = accL[i].y + bvL.y;
        oL.z = accL[i].z + bvL.z; oL.w = accL[i].w + bvL.w;
        oH.x = accH[i].x + bvH.x; oH.y = accH[i].y + bvH.y;
        oH.z = accH[i].z + bvH.z; oH.w = accH[i].w + bvH.w;
        if (mode) {
            oL.x = fmaxf(oL.x, 0.f); oL.y = fmaxf(oL.y, 0.f);
            oL.z = fmaxf(oL.z, 0.f); oL.w = fmaxf(oL.w, 0.f);
            ushort4 obL;
            obL.x = f2bf(oL.x); obL.y = f2bf(oL.y); obL.z = f2bf(oL.z); obL.w = f2bf(oL.w);
            *(ushort4*)((ushort_t*)C + (size_t)gm * NCOL + n0) = obL;
            if (NBN4 == 2) {
                oH.x = fmaxf(oH.x, 0.f); oH.y = fmaxf(oH.y, 0.f);
                oH.z = fmaxf(oH.z, 0.f); oH.w = fmaxf(oH.w, 0.f);
                ushort4 obH;
                obH.x = f2bf(oH.x); obH.y = f2bf(oH.y); obH.z = f2bf(oH.z); obH.w = f2bf(oH.w);
                *(ushort4*)((ushort_t*)C + (size_t)gm * NCOL + n0 + 4) = obH;
            }
        } else {
            *(float4*)((float*)C + (size_t)gm * NCOL + n0) = oL;
            if (NBN4 == 2) *(float4*)((float*)C + (size_t)gm * NCOL + n0 + 4) = oH;
        }
    }
}

extern "C" void kernel_launch(void* const* d_in, const int* in_sizes, int n_in,
                              void* d_out, int out_size, void* d_ws, size_t ws_size,
                              hipStream_t stream) {
    const float* x = (const float*)d_in[0];
    const int* ei = (const int*)d_in[1];
    const float* W1 = (const float*)d_in[2];
    const float* b1 = (const float*)d_in[3];
    const float* Wm = (const float*)d_in[4];
    const float* bm = (const float*)d_in[5];
    const float* W2 = (const float*)d_in[6];
    const float* b2 = (const float*)d_in[7];
    float* out = (float*)d_out;

    const int N = in_sizes[0] / FEAT;      // 100000
    const int E = in_sizes[1] / 2;         // 1600000
    const int NHID = FEAT;                 // 128
    const int OUTD = in_sizes[6] / NHID;   // 64

    const int NBA = (E + EPB - 1) / EPB;   // 98
    const int NBUCK = (N + 255) >> 8;      // 391 (<=512 required)
    const int M = NBUCK * NBA;

    auto alignup = [](size_t v) { return (v + 255) & ~(size_t)255; };
    char* ws = (char*)d_ws;
    size_t off = 0;
    int* G = (int*)(ws + off);           off += alignup((size_t)M * 4);
    int* Gsc = (int*)(ws + off);         off += alignup((size_t)M * 4);
    int* row_start = (int*)(ws + off);   off += alignup((size_t)(N + 1) * 4);
    int* flag = (int*)(ws + off);        off += 256;
    int* col = (int*)(ws + off);         off += alignup((size_t)E * 4);
    ushort_t* Xb = (ushort_t*)(ws + off); off += alignup((size_t)N * FEAT * 2);
    ushort_t* Yb = (ushort_t*)(ws + off); off += alignup((size_t)N * FEAT * 2);
    ushort_t* Hb = (ushort_t*)(ws + off); off += alignup((size_t)N * FEAT * 2);
    // rec (E x 8B = 12.8MB) aliases Yb (25.6MB): consumed by phaseC strictly
    // before agg1 writes Yb.
    uint2* rec = (uint2*)Yb;
    (void)ws_size;

    // --- bf16 table + CSR build ---
    cast_kernel<<<2048, 256, 0, stream>>>(x, Xb, N * FEAT / 4);
    detect_i64_kernel<<<1, 64, 0, stream>>>(ei, flag);
    phaseA_kernel<<<NBA, 256, 0, stream>>>(ei, E, flag, G, NBUCK, NBA);
    scanG_kernel<<<1, 1024, 0, stream>>>(G, Gsc, M);
    phaseB_kernel<<<NBA, 256, 0, stream>>>(ei, E, flag, Gsc, rec, NBUCK, NBA);
    phaseC_kernel<<<NBUCK, 256, 0, stream>>>(rec, Gsc, row_start, col, N, E, NBUCK, NBA);

    const int aggBlocks = (N * 32 + 255) / 256;  // 2 nodes per wave
    const int mlpBlocks = (N + 127) / 128;

    // layer 1
    agg_bf16_kernel<<<aggBlocks, 256, 0, stream>>>(Xb, row_start, col, Yb, N);
    mlp_kernel<128><<<mlpBlocks, 256, 0, stream>>>(Yb, W1, b1, Hb, N, NHID, 1);
    // layer 2
    agg_bf16_kernel<<<aggBlocks, 256, 0, stream>>>(Hb, row_start, col, Yb, N);
    mlp_kernel<128><<<mlpBlocks, 256, 0, stream>>>(Yb, Wm, bm, Hb, N, NHID, 1);
    // layer 3
    agg_bf16_kernel<<<aggBlocks, 256, 0, stream>>>(Hb, row_start, col, Yb, N);
    mlp_kernel<64><<<mlpBlocks, 256, 0, stream>>>(Yb, W2, b2, out, N, OUTD, 0);
}